// Round 10
// baseline (712.275 us; speedup 1.0000x reference)
//
#include <hip/hip_runtime.h>

// LinearAttentionBlock: H(4,8192,1024) f32
// qkv = H@Wqkv^T + b; q,k = elu+1; per (b,h): kv = K^T V, k1 = sum k
// out = (q@kv)/(q.k1); scrambled reshape; @Wproj^T + b; LN; + residual
//
// R9: GEMM1 A-path reg-staged from f32 H with fused cvt (T14 issue-early/
// write-late) -> H bf16 pre-pass eliminated (cvt now weights-only, 12MB).
// kv_partial stages K/V as f32 in LDS (convert once, not 16x per element).

typedef __attribute__((ext_vector_type(4))) float f32x4;
typedef __attribute__((ext_vector_type(8))) short bf16x8;

__device__ __forceinline__ unsigned short f2b(float f) {
    unsigned u = __float_as_uint(f);
    u = (u + 0x7FFFu + ((u >> 16) & 1u)) >> 16;  // RNE
    return (unsigned short)u;
}
__device__ __forceinline__ float b2f(unsigned short h) {
    return __uint_as_float(((unsigned)h) << 16);
}

// async global->LDS, 16B per lane; LDS dest = wave-uniform base + lane*16.
__device__ __forceinline__ void glds16(const void* gp, void* lp) {
    __builtin_amdgcn_global_load_lds(
        (__attribute__((address_space(1))) void*)(unsigned long long)gp,
        (__attribute__((address_space(3))) void*)(unsigned int)(unsigned long long)lp,
        16, 0, 0);
}

// ---------------- fp32 -> bf16 conversion, weights only -------------------
__global__ __launch_bounds__(256) void cvt_w(const float* __restrict__ Wq,
                                             const float* __restrict__ Wp,
                                             unsigned short* __restrict__ wqb,
                                             unsigned short* __restrict__ wpb) {
    const int blk = blockIdx.x;
    const float* src; unsigned short* dst; long n4; int b0, nb;
    if (blk < 128) { src = Wq; dst = wqb; n4 = 786432; b0 = 0;   nb = 128; }
    else           { src = Wp; dst = wpb; n4 = 262144; b0 = 128; nb = 64; }
    long i = (long)(blk - b0) * 256 + threadIdx.x;
    const long stride = (long)nb * 256;
    for (; i < n4; i += stride) {
        float4 v = ((const float4*)src)[i];
        ushort4 o;
        o.x = f2b(v.x); o.y = f2b(v.y); o.z = f2b(v.z); o.w = f2b(v.w);
        ((ushort4*)dst)[i] = o;
    }
}

// ---------------- bf16 MFMA GEMM, C = A @ B^T (+bias), 256^2 8-wave -------
// XCD chunk -> supertile (GROUP_BM=4, bn-inner): per-XCD A panels L2-hot.
// AF32=1: A is fp32; reg-staged (load phase 0, cvt+ds_write phase 2).
// AF32=0: A is bf16 via glds16 (pre-swizzled source).
// MODE 0: v+=bias; col<2048 -> phi; store bf16.  MODE 1: v+=bias; store bf16.
template<int MODE, int AF32>
__global__ __launch_bounds__(512) void gemm256(const void* __restrict__ Ain,
                                               const unsigned short* __restrict__ B,
                                               const float* __restrict__ bias,
                                               void* __restrict__ Cout,
                                               int mb, int N, int K) {
    __shared__ unsigned short lds[2][2][256][64];  // 128 KiB
    const int tid = threadIdx.x;
    const int wid = tid >> 6, lane = tid & 63;
    const int wr = wid >> 2, wc = wid & 3;       // 2M x 4N waves
    const int lr = lane & 15, lq = lane >> 4;
    const int cpx = (int)gridDim.x >> 3;
    const int L = ((int)blockIdx.x & 7) * cpx + ((int)blockIdx.x >> 3);
    const int nbv = N >> 8;
    const int gsz = 4 * nbv;
    const int g = L / gsz, r = L % gsz;
    const int bn = r >> 2;
    const int bm = g * 4 + (r & 3);
    const size_t aRow0 = (size_t)bm * 256, bRow0 = (size_t)bn * 256;

    const int sr8 = lane >> 3;
    const int sl = lane & 7;
    const int ssw = (sl ^ sr8) * 8;              // pre-swizzled source col (elems)
    const unsigned short* aGb = (const unsigned short*)Ain
                                + (aRow0 + (size_t)(wid * 8 + sr8)) * K + ssw;
    const float* aGf = (const float*)Ain
                       + (aRow0 + (size_t)(wid * 8 + sr8)) * K + ssw;
    const unsigned short* bG = B + (bRow0 + (size_t)(wid * 8 + sr8)) * K + ssw;

    f32x4 acc[8][4] = {};
    const char* base = (const char*)&lds[0][0][0][0];
    float4 areg[4][2];                            // in-flight f32 A rows (AF32)

    auto stageB = [&](int buf, int k0) {
#pragma unroll
        for (int j = 0; j < 4; ++j)
            glds16(bG + (size_t)j * 64 * K + k0, &lds[buf][1][j * 64 + wid * 8][0]);
    };
    auto stageAg = [&](int buf, int k0) {         // AF32=0: glds path
#pragma unroll
        for (int j = 0; j < 4; ++j)
            glds16(aGb + (size_t)j * 64 * K + k0, &lds[buf][0][j * 64 + wid * 8][0]);
    };
    auto loadA = [&](int k0) {                    // AF32=1: issue f32 loads
#pragma unroll
        for (int j = 0; j < 4; ++j) {
            const float* src = aGf + (size_t)j * 64 * K + k0;
            areg[j][0] = *(const float4*)(src);
            areg[j][1] = *(const float4*)(src + 4);
        }
    };
    auto writeA = [&](int buf) {                  // AF32=1: cvt + ds_write
#pragma unroll
        for (int j = 0; j < 4; ++j) {
            union { unsigned short us[8]; uint4 u; } o;
            o.us[0] = f2b(areg[j][0].x); o.us[1] = f2b(areg[j][0].y);
            o.us[2] = f2b(areg[j][0].z); o.us[3] = f2b(areg[j][0].w);
            o.us[4] = f2b(areg[j][1].x); o.us[5] = f2b(areg[j][1].y);
            o.us[6] = f2b(areg[j][1].z); o.us[7] = f2b(areg[j][1].w);
            *(uint4*)(&lds[buf][0][j * 64 + wid * 8 + sr8][sl * 8]) = o.u;
        }
    };
    auto ldA = [&](int cur, int mi, int ks) {
        int row = wr * 128 + mi * 16 + lr;
        int off = (cur * 2 + 0) * 32768 + row * 128 + ((((ks << 2) | lq) ^ (row & 7)) << 4);
        return *(const bf16x8*)(base + off);
    };
    auto ldB = [&](int cur, int ni, int ks) {
        int row = wc * 64 + ni * 16 + lr;
        int off = (cur * 2 + 1) * 32768 + row * 128 + ((((ks << 2) | lq) ^ (row & 7)) << 4);
        return *(const bf16x8*)(base + off);
    };

    const int nt = K >> 6;
    // prologue: stage tile 0 into buf 0
    if (AF32) { loadA(0); writeA(0); stageB(0, 0); }
    else      { stageAg(0, 0); stageB(0, 0); }
    __syncthreads();

    bf16x8 af[4][2], bfr[4][2];
    for (int t = 0; t < nt; ++t) {
        const int cur = t & 1;
        // ---- phase 0: frags A mi0-3 + B ni0-1; issue stage(t+1); MFMA Q(0,0)
#pragma unroll
        for (int mi = 0; mi < 4; ++mi) {
            af[mi][0] = ldA(cur, mi, 0); af[mi][1] = ldA(cur, mi, 1);
        }
#pragma unroll
        for (int ni = 0; ni < 2; ++ni) {
            bfr[ni][0] = ldB(cur, ni, 0); bfr[ni][1] = ldB(cur, ni, 1);
        }
        if (t + 1 < nt) {
            if (AF32) { loadA((t + 1) << 6); stageB(cur ^ 1, (t + 1) << 6); }
            else      { stageAg(cur ^ 1, (t + 1) << 6); stageB(cur ^ 1, (t + 1) << 6); }
        }
        __builtin_amdgcn_s_barrier();
        __builtin_amdgcn_s_setprio(1);
#pragma unroll
        for (int mi = 0; mi < 4; ++mi)
#pragma unroll
            for (int ni = 0; ni < 2; ++ni)
#pragma unroll
                for (int ks = 0; ks < 2; ++ks)
                    acc[mi][ni] = __builtin_amdgcn_mfma_f32_16x16x32_bf16(
                        af[mi][ks], bfr[ni][ks], acc[mi][ni], 0, 0, 0);
        __builtin_amdgcn_s_setprio(0);
        __builtin_amdgcn_s_barrier();
        // ---- phase 1: frags B ni2-3; MFMA Q(0,1)
#pragma unroll
        for (int ni = 2; ni < 4; ++ni) {
            bfr[ni][0] = ldB(cur, ni, 0); bfr[ni][1] = ldB(cur, ni, 1);
        }
        __builtin_amdgcn_s_barrier();
        __builtin_amdgcn_s_setprio(1);
#pragma unroll
        for (int mi = 0; mi < 4; ++mi)
#pragma unroll
            for (int ni = 2; ni < 4; ++ni)
#pragma unroll
                for (int ks = 0; ks < 2; ++ks)
                    acc[mi][ni] = __builtin_amdgcn_mfma_f32_16x16x32_bf16(
                        af[mi][ks], bfr[ni][ks], acc[mi][ni], 0, 0, 0);
        __builtin_amdgcn_s_setprio(0);
        __builtin_amdgcn_s_barrier();
        // ---- phase 2: frags A mi4-7; (AF32) cvt+write A(t+1); MFMA Q(1,1)
#pragma unroll
        for (int mi = 0; mi < 4; ++mi) {
            af[mi][0] = ldA(cur, mi + 4, 0); af[mi][1] = ldA(cur, mi + 4, 1);
        }
        if (AF32 && t + 1 < nt) writeA(cur ^ 1);  // compiler inserts vmcnt for areg
        __builtin_amdgcn_s_barrier();
        __builtin_amdgcn_s_setprio(1);
#pragma unroll
        for (int mi = 0; mi < 4; ++mi)
#pragma unroll
            for (int ni = 2; ni < 4; ++ni)
#pragma unroll
                for (int ks = 0; ks < 2; ++ks)
                    acc[mi + 4][ni] = __builtin_amdgcn_mfma_f32_16x16x32_bf16(
                        af[mi][ks], bfr[ni][ks], acc[mi + 4][ni], 0, 0, 0);
        __builtin_amdgcn_s_setprio(0);
        __builtin_amdgcn_s_barrier();
        // ---- phase 3: MFMA Q(1,0) (no reads)
        __builtin_amdgcn_s_setprio(1);
#pragma unroll
        for (int mi = 0; mi < 4; ++mi)
#pragma unroll
            for (int ni = 0; ni < 2; ++ni)
#pragma unroll
                for (int ks = 0; ks < 2; ++ks)
                    acc[mi + 4][ni] = __builtin_amdgcn_mfma_f32_16x16x32_bf16(
                        af[mi][ks], bfr[ni][ks], acc[mi + 4][ni], 0, 0, 0);
        __builtin_amdgcn_s_setprio(0);
        // ---- tile boundary: drain staging (glds + ds_writes), publish
        asm volatile("s_waitcnt vmcnt(0) lgkmcnt(0)" ::: "memory");
        __builtin_amdgcn_s_barrier();
        __builtin_amdgcn_sched_barrier(0);
    }
    // epilogue: C/D layout col=lane&15, row=(lane>>4)*4+reg
#pragma unroll
    for (int mi = 0; mi < 8; ++mi) {
#pragma unroll
        for (int ni = 0; ni < 4; ++ni) {
            int col = (int)bRow0 + wc * 64 + ni * 16 + lr;
            float bv = bias[col];
#pragma unroll
            for (int r2 = 0; r2 < 4; ++r2) {
                size_t row = aRow0 + wr * 128 + mi * 16 + lq * 4 + r2;
                float v = acc[mi][ni][r2] + bv;
                if (MODE == 0) {
                    if (col < 2048) v = (v > 0.f) ? (v + 1.f) : __expf(v);  // elu+1
                }
                ((unsigned short*)Cout)[row * (size_t)N + col] = f2b(v);
            }
        }
    }
}

// ---------------- kv split-K partials: per (b,h,chunk of 1024 rows) -------
// part[(bh*8+chunk)] = [64x64 kv^T (v-major: [v][d]) | 64 k1]  (4160 floats)
// K/V staged as f32 in LDS (convert once; +4 pad kills write conflicts).
__global__ __launch_bounds__(256) void kv_partial(const unsigned short* __restrict__ qkv,
                                                  float* __restrict__ part) {
    const int bh = blockIdx.x, chunk = blockIdx.y;
    const int b = bh >> 4, h = bh & 15;
    __shared__ float kbf[16][68];
    __shared__ float vbf[16][68];
    const int tid = threadIdx.x;
    const int d0 = (tid >> 4) * 4, v0 = (tid & 15) * 4;
    float acc[4][4] = {};
    float k1a[4] = {0.f, 0.f, 0.f, 0.f};
    const size_t base = ((size_t)b * 8192 + (size_t)chunk * 1024) * 3072;
    const int nn = tid >> 4;
    const int which = (tid >> 3) & 1;
    const int cg = tid & 7;
    const size_t loff = base + (size_t)nn * 3072 + (which ? 2048 : 1024) + h * 64 + cg * 8;

    for (int n0 = 0; n0 < 1024; n0 += 16) {
        uint4 val = *(const uint4*)(qkv + loff + (size_t)n0 * 3072);
        float* dst = (which ? &vbf[nn][0] : &kbf[nn][0]) + cg * 8;
        const unsigned short* us = (const unsigned short*)&val;
        float4 f0 = {b2f(us[0]), b2f(us[1]), b2f(us[2]), b2f(us[3])};
        float4 f1 = {b2f(us[4]), b2f(us[5]), b2f(us[6]), b2f(us[7])};
        *(float4*)(dst) = f0;
        *(float4*)(dst + 4) = f1;
        __syncthreads();
#pragma unroll 4
        for (int j = 0; j < 16; ++j) {
            float4 kd = *(const float4*)(&kbf[j][d0]);
            float4 vd = *(const float4*)(&vbf[j][v0]);
            acc[0][0] += kd.x * vd.x; acc[0][1] += kd.x * vd.y; acc[0][2] += kd.x * vd.z; acc[0][3] += kd.x * vd.w;
            acc[1][0] += kd.y * vd.x; acc[1][1] += kd.y * vd.y; acc[1][2] += kd.y * vd.z; acc[1][3] += kd.y * vd.w;
            acc[2][0] += kd.z * vd.x; acc[2][1] += kd.z * vd.y; acc[2][2] += kd.z * vd.z; acc[2][3] += kd.z * vd.w;
            acc[3][0] += kd.w * vd.x; acc[3][1] += kd.w * vd.y; acc[3][2] += kd.w * vd.z; acc[3][3] += kd.w * vd.w;
            if ((tid & 15) == 0) {
                k1a[0] += kd.x; k1a[1] += kd.y; k1a[2] += kd.z; k1a[3] += kd.w;
            }
        }
        __syncthreads();
    }
    float* dst = part + ((size_t)bh * 8 + chunk) * 4160;
#pragma unroll
    for (int i = 0; i < 4; ++i)
#pragma unroll
        for (int jj = 0; jj < 4; ++jj)
            dst[(v0 + jj) * 64 + d0 + i] = acc[i][jj];   // TRANSPOSED: [v][d]
    if ((tid & 15) == 0)
#pragma unroll
        for (int i = 0; i < 4; ++i) dst[4096 + d0 + i] = k1a[i];
}

// ---------------- kv_finish: reduce 8 partials -> bf16 kv^T + f32 k1 ------
__global__ __launch_bounds__(256) void kv_finish(const float* __restrict__ part,
                                                 unsigned short* __restrict__ kvbf,
                                                 float* __restrict__ k1f) {
    const int bh = blockIdx.x;
    const float* src = part + (size_t)bh * 8 * 4160;
    for (int i = threadIdx.x; i < 4096; i += 256) {
        float s = 0.f;
#pragma unroll
        for (int c = 0; c < 8; ++c) s += src[c * 4160 + i];
        kvbf[(size_t)bh * 4096 + i] = f2b(s);
    }
    if (threadIdx.x < 64) {
        float s = 0.f;
#pragma unroll
        for (int c = 0; c < 8; ++c) s += src[c * 4160 + 4096 + threadIdx.x];
        k1f[bh * 64 + threadIdx.x] = s;
    }
}

// ---------------- apply (MFMA): out = (q@kv)/max(q.k1,1e-6), scrambled ----
__global__ __launch_bounds__(256) void apply_attn(const unsigned short* __restrict__ qkv,
                                                  const unsigned short* __restrict__ kvbf,
                                                  const float* __restrict__ k1f,
                                                  unsigned short* __restrict__ att) {
    const int nblk = blockIdx.x;
    const int bh = blockIdx.y;
    const int b = bh >> 4, h = bh & 15;
    __shared__ unsigned short kvs[64][64];   // [v][d], slot-swizzled
    __shared__ float k1s[64];
    __shared__ float qk1s[64];
    const int tid = threadIdx.x;
    {
        const int v = tid >> 3, s = tid & 7;
        const uint4* srcv = (const uint4*)(kvbf + (size_t)bh * 4096);
#pragma unroll
        for (int half = 0; half < 2; ++half) {
            int vv = v + half * 32;
            uint4 val = srcv[vv * 8 + s];
            *(uint4*)(&kvs[vv][(s ^ (vv & 7)) * 8]) = val;
        }
        if (tid < 64) k1s[tid] = k1f[bh * 64 + tid];
    }
    __syncthreads();
    const int n0 = nblk * 64;
    const size_t qbase = ((size_t)b * 8192 + n0) * 3072 + h * 64;
    {
        const int row = tid >> 2, dq = (tid & 3) * 16;
        const unsigned short* qp = qkv + qbase + (size_t)row * 3072 + dq;
        float s = 0.f;
#pragma unroll
        for (int g2 = 0; g2 < 2; ++g2) {
            ushort4 u0 = *(const ushort4*)(qp + g2 * 8);
            ushort4 u1 = *(const ushort4*)(qp + g2 * 8 + 4);
            const float* kp = &k1s[dq + g2 * 8];
            s += b2f(u0.x) * kp[0] + b2f(u0.y) * kp[1] + b2f(u0.z) * kp[2] + b2f(u0.w) * kp[3]
               + b2f(u1.x) * kp[4] + b2f(u1.y) * kp[5] + b2f(u1.z) * kp[6] + b2f(u1.w) * kp[7];
        }
        s += __shfl_xor(s, 1, 64);
        s += __shfl_xor(s, 2, 64);
        if ((tid & 3) == 0) qk1s[row] = s;
    }
    __syncthreads();
    const int w = tid >> 6, lane = tid & 63;
    const int lr = lane & 15, lq = lane >> 4;
    bf16x8 af[2];
#pragma unroll
    for (int ks = 0; ks < 2; ++ks)
        af[ks] = *(const bf16x8*)(qkv + qbase + (size_t)(w * 16 + lr) * 3072 + ks * 32 + lq * 8);
    f32x4 acc[4] = {};
#pragma unroll
    for (int ni = 0; ni < 4; ++ni)
#pragma unroll
        for (int ks = 0; ks < 2; ++ks) {
            int v = ni * 16 + lr;
            bf16x8 bf = *(const bf16x8*)(&kvs[v][(((ks << 2) | lq) ^ (v & 7)) * 8]);
            acc[ni] = __builtin_amdgcn_mfma_f32_16x16x32_bf16(af[ks], bf, acc[ni], 0, 0, 0);
        }
    unsigned short* dstrow = att + (((size_t)b * 8192) + h * 512 + nblk * 4 + w) * 1024;
#pragma unroll
    for (int r = 0; r < 4; ++r) {
        float rinv = 1.f / fmaxf(qk1s[w * 16 + lq * 4 + r], 1e-6f);
#pragma unroll
        for (int ni = 0; ni < 4; ++ni)
            dstrow[(lq * 4 + r) * 64 + ni * 16 + lr] = f2b(acc[ni][r] * rinv);
    }
}

// ---------------- LayerNorm + residual, 1 wave per row, barrier-free ------
__global__ __launch_bounds__(256) void ln_residual(const unsigned short* __restrict__ X,
                                                   const float* __restrict__ H,
                                                   const float* __restrict__ gamma,
                                                   const float* __restrict__ beta,
                                                   float* __restrict__ out,
                                                   int nrows) {
    const int lane = threadIdx.x & 63;
    int row = blockIdx.x * 4 + (threadIdx.x >> 6);
    const int rstride = gridDim.x * 4;
    for (; row < nrows; row += rstride) {
        const unsigned short* x = X + (size_t)row * 1024;
        float v[16];
        float s = 0.f, s2 = 0.f;
#pragma unroll
        for (int j = 0; j < 4; ++j) {
            ushort4 u = *(const ushort4*)(x + j * 256 + lane * 4);
            float a = b2f(u.x), b = b2f(u.y), c = b2f(u.z), d = b2f(u.w);
            v[j * 4 + 0] = a; v[j * 4 + 1] = b; v[j * 4 + 2] = c; v[j * 4 + 3] = d;
            s += a + b + c + d;
            s2 += a * a + b * b + c * c + d * d;
        }
#pragma unroll
        for (int o = 32; o > 0; o >>= 1) {
            s  += __shfl_xor(s, o, 64);
            s2 += __shfl_xor(s2, o, 64);
        }
        const float mu = s * (1.f / 1024.f);
        const float var = s2 * (1.f / 1024.f) - mu * mu;   // biased var (jnp.var)
        const float inv = rsqrtf(var + 1e-5f);
        const float* hrow = H + (size_t)row * 1024;
        float* orow = out + (size_t)row * 1024;
#pragma unroll
        for (int j = 0; j < 4; ++j) {
            const int c = j * 256 + lane * 4;
            float4 g = *(const float4*)(gamma + c);
            float4 bt = *(const float4*)(beta + c);
            float4 hr = *(const float4*)(hrow + c);
            float4 o;
            o.x = (v[j * 4 + 0] - mu) * inv * g.x + bt.x + hr.x;
            o.y = (v[j * 4 + 1] - mu) * inv * g.y + bt.y + hr.y;
            o.z = (v[j * 4 + 2] - mu) * inv * g.z + bt.z + hr.z;
            o.w = (v[j * 4 + 3] - mu) * inv * g.w + bt.w + hr.w;
            *(float4*)(orow + c) = o;
        }
    }
}

// ---------------------------------------------------------------------------
extern "C" void kernel_launch(void* const* d_in, const int* in_sizes, int n_in,
                              void* d_out, int out_size, void* d_ws, size_t ws_size,
                              hipStream_t stream) {
    const float* H     = (const float*)d_in[0];
    const float* Wqkv  = (const float*)d_in[1];
    const float* bqkv  = (const float*)d_in[2];
    const float* Wproj = (const float*)d_in[3];
    const float* bproj = (const float*)d_in[4];
    const float* gamma = (const float*)d_in[5];
    const float* beta  = (const float*)d_in[6];
    float* out = (float*)d_out;
    char* ws = (char*)d_ws;

    // ws layout (bytes); out2 aliases qkvbf (disjoint lifetimes)
    unsigned short* wq_bf = (unsigned short*)(ws);                 //   6,291,456
    unsigned short* wp_bf = (unsigned short*)(ws + 6291456);       //   2,097,152
    unsigned short* att   = (unsigned short*)(ws + 8388608);       //  67,108,864
    unsigned short* qkvbf = (unsigned short*)(ws + 75497472);      // 201,326,592
    unsigned short* out2  = (unsigned short*)(ws + 75497472);      // bf16, 67MB
    unsigned short* kvbf  = (unsigned short*)(ws + 276824064);     //     524,288
    float*          k1f   = (float*)(ws + 277348352);              //      16,384
    float*          part  = (float*)(ws + 277889024);              //   8,519,680

    cvt_w<<<192, 256, 0, stream>>>(Wqkv, Wproj, wq_bf, wp_bf);

    // GEMM1: A = H (f32, fused cvt); M=32768 (mb=128), N=3072 -> grid 1536
    gemm256<0, 1><<<1536, 512, 0, stream>>>((const void*)H, wq_bf, bqkv,
                                            (void*)qkvbf, 128, 3072, 1024);

    kv_partial<<<dim3(64, 8), 256, 0, stream>>>(qkvbf, part);
    kv_finish<<<64, 256, 0, stream>>>(part, kvbf, k1f);

    apply_attn<<<dim3(128, 64), 256, 0, stream>>>(qkvbf, kvbf, k1f, att);

    // GEMM2: A = att (bf16); M=32768 (mb=128), N=1024 -> grid 512
    gemm256<1, 0><<<512, 512, 0, stream>>>((const void*)att, wp_bf, bproj,
                                           (void*)out2, 128, 1024, 1024);

    ln_residual<<<2048, 256, 0, stream>>>(out2, H, gamma, beta, out, 32768);
}

// Round 11
// 536.277 us; speedup vs baseline: 1.3282x; 1.3282x over previous
//
#include <hip/hip_runtime.h>

// LinearAttentionBlock: H(4,8192,1024) f32
// qkv = H@Wqkv^T + b; q,k = elu+1; per (b,h): kv = K^T V, k1 = sum k
// out = (q@kv)/(q.k1); scrambled reshape; @Wproj^T + b; LN; + residual
//
// R10: revert R9's fused-cvt reg-staged GEMM1 (474us vs 253us: f32 A panels
// blew the 4MiB/XCD L2 supertile budget + per-tile lgkmcnt(0) ds_write drain
// stalled the lockstep schedule). Back to R8's bf16-A glds16 GEMM (253us).
// Kept: kv_partial f32-LDS staging, MFMA apply, kv_finish, supertile order.

typedef __attribute__((ext_vector_type(4))) float f32x4;
typedef __attribute__((ext_vector_type(8))) short bf16x8;

__device__ __forceinline__ unsigned short f2b(float f) {
    unsigned u = __float_as_uint(f);
    u = (u + 0x7FFFu + ((u >> 16) & 1u)) >> 16;  // RNE
    return (unsigned short)u;
}
__device__ __forceinline__ float b2f(unsigned short h) {
    return __uint_as_float(((unsigned)h) << 16);
}

// async global->LDS, 16B per lane; LDS dest = wave-uniform base + lane*16.
__device__ __forceinline__ void glds16(const void* gp, void* lp) {
    __builtin_amdgcn_global_load_lds(
        (__attribute__((address_space(1))) void*)(unsigned long long)gp,
        (__attribute__((address_space(3))) void*)(unsigned int)(unsigned long long)lp,
        16, 0, 0);
}

// ---------------- fp32 -> bf16 conversion, all 3 inputs in one launch -----
__global__ __launch_bounds__(256) void cvt_all(const float* __restrict__ H,
                                               const float* __restrict__ Wq,
                                               const float* __restrict__ Wp,
                                               unsigned short* __restrict__ hbf,
                                               unsigned short* __restrict__ wqb,
                                               unsigned short* __restrict__ wpb) {
    const int blk = blockIdx.x;
    const float* src; unsigned short* dst; long n4; int b0, nb;
    if (blk < 1792)      { src = H;  dst = hbf; n4 = 8388608; b0 = 0;    nb = 1792; }
    else if (blk < 1920) { src = Wq; dst = wqb; n4 = 786432;  b0 = 1792; nb = 128; }
    else                 { src = Wp; dst = wpb; n4 = 262144;  b0 = 1920; nb = 64; }
    long i = (long)(blk - b0) * 256 + threadIdx.x;
    const long stride = (long)nb * 256;
    for (; i < n4; i += stride) {
        float4 v = ((const float4*)src)[i];
        ushort4 o;
        o.x = f2b(v.x); o.y = f2b(v.y); o.z = f2b(v.z); o.w = f2b(v.w);
        ((ushort4*)dst)[i] = o;
    }
}

// ---------------- bf16 MFMA GEMM, C = A @ B^T (+bias), 256^2 8-wave -------
// XCD chunk -> supertile (GROUP_BM=4, bn-inner): per-XCD A panels L2-hot.
// MODE 0: v+=bias; col<2048 -> phi; store bf16.  MODE 1: v+=bias; store bf16.
template<int MODE>
__global__ __launch_bounds__(512) void gemm256(const unsigned short* __restrict__ A,
                                               const unsigned short* __restrict__ B,
                                               const float* __restrict__ bias,
                                               void* __restrict__ Cout,
                                               int mb, int N, int K) {
    __shared__ unsigned short lds[2][2][256][64];  // 128 KiB
    const int tid = threadIdx.x;
    const int wid = tid >> 6, lane = tid & 63;
    const int wr = wid >> 2, wc = wid & 3;       // 2M x 4N waves
    const int lr = lane & 15, lq = lane >> 4;
    const int cpx = (int)gridDim.x >> 3;
    const int L = ((int)blockIdx.x & 7) * cpx + ((int)blockIdx.x >> 3);
    const int nbv = N >> 8;
    const int gsz = 4 * nbv;
    const int g = L / gsz, r = L % gsz;
    const int bn = r >> 2;
    const int bm = g * 4 + (r & 3);
    const size_t aRow0 = (size_t)bm * 256, bRow0 = (size_t)bn * 256;

    const int sr8 = lane >> 3;
    const int ssw = ((lane & 7) ^ sr8) * 8;      // pre-swizzled source col
    const unsigned short* aG = A + (aRow0 + (size_t)(wid * 8 + sr8)) * K + ssw;
    const unsigned short* bG = B + (bRow0 + (size_t)(wid * 8 + sr8)) * K + ssw;

    f32x4 acc[8][4] = {};
    const char* base = (const char*)&lds[0][0][0][0];

    auto stage = [&](int buf, int k0) {
#pragma unroll
        for (int j = 0; j < 8; ++j) {
            const unsigned short* g2 = (j < 4 ? aG : bG) + (size_t)(j & 3) * 64 * K + k0;
            glds16(g2, &lds[buf][j >> 2][(j & 3) * 64 + wid * 8][0]);
        }
    };
    auto ldA = [&](int cur, int mi, int ks) {
        int row = wr * 128 + mi * 16 + lr;
        int off = (cur * 2 + 0) * 32768 + row * 128 + ((((ks << 2) | lq) ^ (row & 7)) << 4);
        return *(const bf16x8*)(base + off);
    };
    auto ldB = [&](int cur, int ni, int ks) {
        int row = wc * 64 + ni * 16 + lr;
        int off = (cur * 2 + 1) * 32768 + row * 128 + ((((ks << 2) | lq) ^ (row & 7)) << 4);
        return *(const bf16x8*)(base + off);
    };

    const int nt = K >> 6;
    stage(0, 0);
    asm volatile("s_waitcnt vmcnt(0)" ::: "memory");
    __builtin_amdgcn_s_barrier();

    bf16x8 af[4][2], bfr[4][2];
    for (int t = 0; t < nt; ++t) {
        const int cur = t & 1;
        // ---- phase 0: frags A mi0-3 + B ni0-1; issue stage(t+1); MFMA Q(0,0)
#pragma unroll
        for (int mi = 0; mi < 4; ++mi) {
            af[mi][0] = ldA(cur, mi, 0); af[mi][1] = ldA(cur, mi, 1);
        }
#pragma unroll
        for (int ni = 0; ni < 2; ++ni) {
            bfr[ni][0] = ldB(cur, ni, 0); bfr[ni][1] = ldB(cur, ni, 1);
        }
        if (t + 1 < nt) stage(cur ^ 1, (t + 1) << 6);
        __builtin_amdgcn_s_barrier();
        __builtin_amdgcn_s_setprio(1);
#pragma unroll
        for (int mi = 0; mi < 4; ++mi)
#pragma unroll
            for (int ni = 0; ni < 2; ++ni)
#pragma unroll
                for (int ks = 0; ks < 2; ++ks)
                    acc[mi][ni] = __builtin_amdgcn_mfma_f32_16x16x32_bf16(
                        af[mi][ks], bfr[ni][ks], acc[mi][ni], 0, 0, 0);
        __builtin_amdgcn_s_setprio(0);
        __builtin_amdgcn_s_barrier();
        // ---- phase 1: frags B ni2-3; MFMA Q(0,1)
#pragma unroll
        for (int ni = 2; ni < 4; ++ni) {
            bfr[ni][0] = ldB(cur, ni, 0); bfr[ni][1] = ldB(cur, ni, 1);
        }
        __builtin_amdgcn_s_barrier();
        __builtin_amdgcn_s_setprio(1);
#pragma unroll
        for (int mi = 0; mi < 4; ++mi)
#pragma unroll
            for (int ni = 2; ni < 4; ++ni)
#pragma unroll
                for (int ks = 0; ks < 2; ++ks)
                    acc[mi][ni] = __builtin_amdgcn_mfma_f32_16x16x32_bf16(
                        af[mi][ks], bfr[ni][ks], acc[mi][ni], 0, 0, 0);
        __builtin_amdgcn_s_setprio(0);
        __builtin_amdgcn_s_barrier();
        // ---- phase 2: frags A mi4-7; MFMA Q(1,1)
#pragma unroll
        for (int mi = 0; mi < 4; ++mi) {
            af[mi][0] = ldA(cur, mi + 4, 0); af[mi][1] = ldA(cur, mi + 4, 1);
        }
        __builtin_amdgcn_s_barrier();
        __builtin_amdgcn_s_setprio(1);
#pragma unroll
        for (int mi = 0; mi < 4; ++mi)
#pragma unroll
            for (int ni = 2; ni < 4; ++ni)
#pragma unroll
                for (int ks = 0; ks < 2; ++ks)
                    acc[mi + 4][ni] = __builtin_amdgcn_mfma_f32_16x16x32_bf16(
                        af[mi][ks], bfr[ni][ks], acc[mi + 4][ni], 0, 0, 0);
        __builtin_amdgcn_s_setprio(0);
        __builtin_amdgcn_s_barrier();
        // ---- phase 3: MFMA Q(1,0) (no reads)
        __builtin_amdgcn_s_setprio(1);
#pragma unroll
        for (int mi = 0; mi < 4; ++mi)
#pragma unroll
            for (int ni = 0; ni < 2; ++ni)
#pragma unroll
                for (int ks = 0; ks < 2; ++ks)
                    acc[mi + 4][ni] = __builtin_amdgcn_mfma_f32_16x16x32_bf16(
                        af[mi][ks], bfr[ni][ks], acc[mi + 4][ni], 0, 0, 0);
        __builtin_amdgcn_s_setprio(0);
        // ---- tile boundary: next buffer landed; all reads of cur done
        asm volatile("s_waitcnt vmcnt(0)" ::: "memory");
        __builtin_amdgcn_s_barrier();
        __builtin_amdgcn_sched_barrier(0);
    }
    // epilogue: C/D layout col=lane&15, row=(lane>>4)*4+reg
#pragma unroll
    for (int mi = 0; mi < 8; ++mi) {
#pragma unroll
        for (int ni = 0; ni < 4; ++ni) {
            int col = (int)bRow0 + wc * 64 + ni * 16 + lr;
            float bv = bias[col];
#pragma unroll
            for (int r2 = 0; r2 < 4; ++r2) {
                size_t row = aRow0 + wr * 128 + mi * 16 + lq * 4 + r2;
                float v = acc[mi][ni][r2] + bv;
                if (MODE == 0) {
                    if (col < 2048) v = (v > 0.f) ? (v + 1.f) : __expf(v);  // elu+1
                }
                ((unsigned short*)Cout)[row * (size_t)N + col] = f2b(v);
            }
        }
    }
}

// ---------------- kv split-K partials: per (b,h,chunk of 1024 rows) -------
// part[(bh*8+chunk)] = [64x64 kv^T (v-major: [v][d]) | 64 k1]  (4160 floats)
// K/V staged as f32 in LDS (convert once; +4 pad kills write conflicts).
__global__ __launch_bounds__(256) void kv_partial(const unsigned short* __restrict__ qkv,
                                                  float* __restrict__ part) {
    const int bh = blockIdx.x, chunk = blockIdx.y;
    const int b = bh >> 4, h = bh & 15;
    __shared__ float kbf[16][68];
    __shared__ float vbf[16][68];
    const int tid = threadIdx.x;
    const int d0 = (tid >> 4) * 4, v0 = (tid & 15) * 4;
    float acc[4][4] = {};
    float k1a[4] = {0.f, 0.f, 0.f, 0.f};
    const size_t base = ((size_t)b * 8192 + (size_t)chunk * 1024) * 3072;
    const int nn = tid >> 4;
    const int which = (tid >> 3) & 1;
    const int cg = tid & 7;
    const size_t loff = base + (size_t)nn * 3072 + (which ? 2048 : 1024) + h * 64 + cg * 8;

    for (int n0 = 0; n0 < 1024; n0 += 16) {
        uint4 val = *(const uint4*)(qkv + loff + (size_t)n0 * 3072);
        float* dst = (which ? &vbf[nn][0] : &kbf[nn][0]) + cg * 8;
        const unsigned short* us = (const unsigned short*)&val;
        float4 f0 = {b2f(us[0]), b2f(us[1]), b2f(us[2]), b2f(us[3])};
        float4 f1 = {b2f(us[4]), b2f(us[5]), b2f(us[6]), b2f(us[7])};
        *(float4*)(dst) = f0;
        *(float4*)(dst + 4) = f1;
        __syncthreads();
#pragma unroll 4
        for (int j = 0; j < 16; ++j) {
            float4 kd = *(const float4*)(&kbf[j][d0]);
            float4 vd = *(const float4*)(&vbf[j][v0]);
            acc[0][0] += kd.x * vd.x; acc[0][1] += kd.x * vd.y; acc[0][2] += kd.x * vd.z; acc[0][3] += kd.x * vd.w;
            acc[1][0] += kd.y * vd.x; acc[1][1] += kd.y * vd.y; acc[1][2] += kd.y * vd.z; acc[1][3] += kd.y * vd.w;
            acc[2][0] += kd.z * vd.x; acc[2][1] += kd.z * vd.y; acc[2][2] += kd.z * vd.z; acc[2][3] += kd.z * vd.w;
            acc[3][0] += kd.w * vd.x; acc[3][1] += kd.w * vd.y; acc[3][2] += kd.w * vd.z; acc[3][3] += kd.w * vd.w;
            if ((tid & 15) == 0) {
                k1a[0] += kd.x; k1a[1] += kd.y; k1a[2] += kd.z; k1a[3] += kd.w;
            }
        }
        __syncthreads();
    }
    float* dst = part + ((size_t)bh * 8 + chunk) * 4160;
#pragma unroll
    for (int i = 0; i < 4; ++i)
#pragma unroll
        for (int jj = 0; jj < 4; ++jj)
            dst[(v0 + jj) * 64 + d0 + i] = acc[i][jj];   // TRANSPOSED: [v][d]
    if ((tid & 15) == 0)
#pragma unroll
        for (int i = 0; i < 4; ++i) dst[4096 + d0 + i] = k1a[i];
}

// ---------------- kv_finish: reduce 8 partials -> bf16 kv^T + f32 k1 ------
__global__ __launch_bounds__(256) void kv_finish(const float* __restrict__ part,
                                                 unsigned short* __restrict__ kvbf,
                                                 float* __restrict__ k1f) {
    const int bh = blockIdx.x;
    const float* src = part + (size_t)bh * 8 * 4160;
    for (int i = threadIdx.x; i < 4096; i += 256) {
        float s = 0.f;
#pragma unroll
        for (int c = 0; c < 8; ++c) s += src[c * 4160 + i];
        kvbf[(size_t)bh * 4096 + i] = f2b(s);
    }
    if (threadIdx.x < 64) {
        float s = 0.f;
#pragma unroll
        for (int c = 0; c < 8; ++c) s += src[c * 4160 + 4096 + threadIdx.x];
        k1f[bh * 64 + threadIdx.x] = s;
    }
}

// ---------------- apply (MFMA): out = (q@kv)/max(q.k1,1e-6), scrambled ----
__global__ __launch_bounds__(256) void apply_attn(const unsigned short* __restrict__ qkv,
                                                  const unsigned short* __restrict__ kvbf,
                                                  const float* __restrict__ k1f,
                                                  unsigned short* __restrict__ att) {
    const int nblk = blockIdx.x;
    const int bh = blockIdx.y;
    const int b = bh >> 4, h = bh & 15;
    __shared__ unsigned short kvs[64][64];   // [v][d], slot-swizzled
    __shared__ float k1s[64];
    __shared__ float qk1s[64];
    const int tid = threadIdx.x;
    {
        const int v = tid >> 3, s = tid & 7;
        const uint4* srcv = (const uint4*)(kvbf + (size_t)bh * 4096);
#pragma unroll
        for (int half = 0; half < 2; ++half) {
            int vv = v + half * 32;
            uint4 val = srcv[vv * 8 + s];
            *(uint4*)(&kvs[vv][(s ^ (vv & 7)) * 8]) = val;
        }
        if (tid < 64) k1s[tid] = k1f[bh * 64 + tid];
    }
    __syncthreads();
    const int n0 = nblk * 64;
    const size_t qbase = ((size_t)b * 8192 + n0) * 3072 + h * 64;
    {
        const int row = tid >> 2, dq = (tid & 3) * 16;
        const unsigned short* qp = qkv + qbase + (size_t)row * 3072 + dq;
        float s = 0.f;
#pragma unroll
        for (int g2 = 0; g2 < 2; ++g2) {
            ushort4 u0 = *(const ushort4*)(qp + g2 * 8);
            ushort4 u1 = *(const ushort4*)(qp + g2 * 8 + 4);
            const float* kp = &k1s[dq + g2 * 8];
            s += b2f(u0.x) * kp[0] + b2f(u0.y) * kp[1] + b2f(u0.z) * kp[2] + b2f(u0.w) * kp[3]
               + b2f(u1.x) * kp[4] + b2f(u1.y) * kp[5] + b2f(u1.z) * kp[6] + b2f(u1.w) * kp[7];
        }
        s += __shfl_xor(s, 1, 64);
        s += __shfl_xor(s, 2, 64);
        if ((tid & 3) == 0) qk1s[row] = s;
    }
    __syncthreads();
    const int w = tid >> 6, lane = tid & 63;
    const int lr = lane & 15, lq = lane >> 4;
    bf16x8 af[2];
#pragma unroll
    for (int ks = 0; ks < 2; ++ks)
        af[ks] = *(const bf16x8*)(qkv + qbase + (size_t)(w * 16 + lr) * 3072 + ks * 32 + lq * 8);
    f32x4 acc[4] = {};
#pragma unroll
    for (int ni = 0; ni < 4; ++ni)
#pragma unroll
        for (int ks = 0; ks < 2; ++ks) {
            int v = ni * 16 + lr;
            bf16x8 bf = *(const bf16x8*)(&kvs[v][(((ks << 2) | lq) ^ (v & 7)) * 8]);
            acc[ni] = __builtin_amdgcn_mfma_f32_16x16x32_bf16(af[ks], bf, acc[ni], 0, 0, 0);
        }
    unsigned short* dstrow = att + (((size_t)b * 8192) + h * 512 + nblk * 4 + w) * 1024;
#pragma unroll
    for (int r = 0; r < 4; ++r) {
        float rinv = 1.f / fmaxf(qk1s[w * 16 + lq * 4 + r], 1e-6f);
#pragma unroll
        for (int ni = 0; ni < 4; ++ni)
            dstrow[(lq * 4 + r) * 64 + ni * 16 + lr] = f2b(acc[ni][r] * rinv);
    }
}

// ---------------- LayerNorm + residual, 1 wave per row, barrier-free ------
__global__ __launch_bounds__(256) void ln_residual(const unsigned short* __restrict__ X,
                                                   const float* __restrict__ H,
                                                   const float* __restrict__ gamma,
                                                   const float* __restrict__ beta,
                                                   float* __restrict__ out,
                                                   int nrows) {
    const int lane = threadIdx.x & 63;
    int row = blockIdx.x * 4 + (threadIdx.x >> 6);
    const int rstride = gridDim.x * 4;
    for (; row < nrows; row += rstride) {
        const unsigned short* x = X + (size_t)row * 1024;
        float v[16];
        float s = 0.f, s2 = 0.f;
#pragma unroll
        for (int j = 0; j < 4; ++j) {
            ushort4 u = *(const ushort4*)(x + j * 256 + lane * 4);
            float a = b2f(u.x), b = b2f(u.y), c = b2f(u.z), d = b2f(u.w);
            v[j * 4 + 0] = a; v[j * 4 + 1] = b; v[j * 4 + 2] = c; v[j * 4 + 3] = d;
            s += a + b + c + d;
            s2 += a * a + b * b + c * c + d * d;
        }
#pragma unroll
        for (int o = 32; o > 0; o >>= 1) {
            s  += __shfl_xor(s, o, 64);
            s2 += __shfl_xor(s2, o, 64);
        }
        const float mu = s * (1.f / 1024.f);
        const float var = s2 * (1.f / 1024.f) - mu * mu;   // biased var (jnp.var)
        const float inv = rsqrtf(var + 1e-5f);
        const float* hrow = H + (size_t)row * 1024;
        float* orow = out + (size_t)row * 1024;
#pragma unroll
        for (int j = 0; j < 4; ++j) {
            const int c = j * 256 + lane * 4;
            float4 g = *(const float4*)(gamma + c);
            float4 bt = *(const float4*)(beta + c);
            float4 hr = *(const float4*)(hrow + c);
            float4 o;
            o.x = (v[j * 4 + 0] - mu) * inv * g.x + bt.x + hr.x;
            o.y = (v[j * 4 + 1] - mu) * inv * g.y + bt.y + hr.y;
            o.z = (v[j * 4 + 2] - mu) * inv * g.z + bt.z + hr.z;
            o.w = (v[j * 4 + 3] - mu) * inv * g.w + bt.w + hr.w;
            *(float4*)(orow + c) = o;
        }
    }
}

// ---------------------------------------------------------------------------
extern "C" void kernel_launch(void* const* d_in, const int* in_sizes, int n_in,
                              void* d_out, int out_size, void* d_ws, size_t ws_size,
                              hipStream_t stream) {
    const float* H     = (const float*)d_in[0];
    const float* Wqkv  = (const float*)d_in[1];
    const float* bqkv  = (const float*)d_in[2];
    const float* Wproj = (const float*)d_in[3];
    const float* bproj = (const float*)d_in[4];
    const float* gamma = (const float*)d_in[5];
    const float* beta  = (const float*)d_in[6];
    float* out = (float*)d_out;
    char* ws = (char*)d_ws;

    // ws layout (bytes); att aliases hbf, out2 aliases qkvbf (disjoint lifetimes)
    unsigned short* wq_bf = (unsigned short*)(ws);                 //   6,291,456
    unsigned short* wp_bf = (unsigned short*)(ws + 6291456);       //   2,097,152
    unsigned short* hbf   = (unsigned short*)(ws + 8388608);       //  67,108,864
    unsigned short* att   = hbf;
    unsigned short* qkvbf = (unsigned short*)(ws + 75497472);      // 201,326,592
    unsigned short* out2  = (unsigned short*)(ws + 75497472);      // bf16, 67MB
    unsigned short* kvbf  = (unsigned short*)(ws + 276824064);     //     524,288
    float*          k1f   = (float*)(ws + 277348352);              //      16,384
    float*          part  = (float*)(ws + 277889024);              //   8,519,680

    cvt_all<<<1984, 256, 0, stream>>>(H, Wqkv, Wproj, hbf, wq_bf, wp_bf);

    // GEMM1: M=32768 (mb=128), N=3072 -> grid 128*12 = 1536 (%8==0)
    gemm256<0><<<1536, 512, 0, stream>>>(hbf, wq_bf, bqkv, (void*)qkvbf,
                                         128, 3072, 1024);

    kv_partial<<<dim3(64, 8), 256, 0, stream>>>(qkvbf, part);
    kv_finish<<<64, 256, 0, stream>>>(part, kvbf, k1f);

    apply_attn<<<dim3(128, 64), 256, 0, stream>>>(qkvbf, kvbf, k1f, att);

    // GEMM2: M=32768 (mb=128), N=1024 -> grid 128*4 = 512 (%8==0); bf16 out
    gemm256<1><<<512, 512, 0, stream>>>(att, wp_bf, bproj, (void*)out2,
                                        128, 1024, 1024);

    ln_residual<<<2048, 256, 0, stream>>>(out2, H, gamma, beta, out, 32768);
}

// Round 12
// 522.867 us; speedup vs baseline: 1.3623x; 1.0256x over previous
//
#include <hip/hip_runtime.h>

// LinearAttentionBlock: H(4,8192,1024) f32
// qkv = H@Wqkv^T + b; q,k = elu+1; per (b,h): kv = K^T V, k1 = sum k
// out = (q@kv)/(q.k1); scrambled reshape; @Wproj^T + b; LN; + residual
//
// R11: planar q/k/v buffers (GEMM1 epilogue routes by col>>10). att aliases
// kbuf, out2 aliases vbuf -> hbf stays live to the end, so LN residual reads
// bf16 hbf (-67MB traffic). Same 286.4MB ws footprint. GEMM structure
// unchanged (253us = verified plain-HIP plateau at K=1024).

typedef __attribute__((ext_vector_type(4))) float f32x4;
typedef __attribute__((ext_vector_type(8))) short bf16x8;

__device__ __forceinline__ unsigned short f2b(float f) {
    unsigned u = __float_as_uint(f);
    u = (u + 0x7FFFu + ((u >> 16) & 1u)) >> 16;  // RNE
    return (unsigned short)u;
}
__device__ __forceinline__ float b2f(unsigned short h) {
    return __uint_as_float(((unsigned)h) << 16);
}

// async global->LDS, 16B per lane; LDS dest = wave-uniform base + lane*16.
__device__ __forceinline__ void glds16(const void* gp, void* lp) {
    __builtin_amdgcn_global_load_lds(
        (__attribute__((address_space(1))) void*)(unsigned long long)gp,
        (__attribute__((address_space(3))) void*)(unsigned int)(unsigned long long)lp,
        16, 0, 0);
}

// ---------------- fp32 -> bf16 conversion, all 3 inputs in one launch -----
__global__ __launch_bounds__(256) void cvt_all(const float* __restrict__ H,
                                               const float* __restrict__ Wq,
                                               const float* __restrict__ Wp,
                                               unsigned short* __restrict__ hbf,
                                               unsigned short* __restrict__ wqb,
                                               unsigned short* __restrict__ wpb) {
    const int blk = blockIdx.x;
    const float* src; unsigned short* dst; long n4; int b0, nb;
    if (blk < 1792)      { src = H;  dst = hbf; n4 = 8388608; b0 = 0;    nb = 1792; }
    else if (blk < 1920) { src = Wq; dst = wqb; n4 = 786432;  b0 = 1792; nb = 128; }
    else                 { src = Wp; dst = wpb; n4 = 262144;  b0 = 1920; nb = 64; }
    long i = (long)(blk - b0) * 256 + threadIdx.x;
    const long stride = (long)nb * 256;
    for (; i < n4; i += stride) {
        float4 v = ((const float4*)src)[i];
        ushort4 o;
        o.x = f2b(v.x); o.y = f2b(v.y); o.z = f2b(v.z); o.w = f2b(v.w);
        ((ushort4*)dst)[i] = o;
    }
}

// ---------------- bf16 MFMA GEMM, C = A @ B^T (+bias), 256^2 8-wave -------
// XCD chunk -> supertile (GROUP_BM=4, bn-inner): per-XCD A panels L2-hot.
// MODE 0: v+=bias; col<2048 -> phi; PLANAR store: plane=col>>10 (q/k/v each
//         M x 1024, consecutive 32M-elem planes starting at Cout).
// MODE 1: v+=bias; store bf16 row-major M x N.
template<int MODE>
__global__ __launch_bounds__(512) void gemm256(const unsigned short* __restrict__ A,
                                               const unsigned short* __restrict__ B,
                                               const float* __restrict__ bias,
                                               void* __restrict__ Cout,
                                               int mb, int N, int K) {
    __shared__ unsigned short lds[2][2][256][64];  // 128 KiB
    const int tid = threadIdx.x;
    const int wid = tid >> 6, lane = tid & 63;
    const int wr = wid >> 2, wc = wid & 3;       // 2M x 4N waves
    const int lr = lane & 15, lq = lane >> 4;
    const int cpx = (int)gridDim.x >> 3;
    const int L = ((int)blockIdx.x & 7) * cpx + ((int)blockIdx.x >> 3);
    const int nbv = N >> 8;
    const int gsz = 4 * nbv;
    const int g = L / gsz, r = L % gsz;
    const int bn = r >> 2;
    const int bm = g * 4 + (r & 3);
    const size_t aRow0 = (size_t)bm * 256, bRow0 = (size_t)bn * 256;

    const int sr8 = lane >> 3;
    const int ssw = ((lane & 7) ^ sr8) * 8;      // pre-swizzled source col
    const unsigned short* aG = A + (aRow0 + (size_t)(wid * 8 + sr8)) * K + ssw;
    const unsigned short* bG = B + (bRow0 + (size_t)(wid * 8 + sr8)) * K + ssw;

    f32x4 acc[8][4] = {};
    const char* base = (const char*)&lds[0][0][0][0];

    auto stage = [&](int buf, int k0) {
#pragma unroll
        for (int j = 0; j < 8; ++j) {
            const unsigned short* g2 = (j < 4 ? aG : bG) + (size_t)(j & 3) * 64 * K + k0;
            glds16(g2, &lds[buf][j >> 2][(j & 3) * 64 + wid * 8][0]);
        }
    };
    auto ldA = [&](int cur, int mi, int ks) {
        int row = wr * 128 + mi * 16 + lr;
        int off = (cur * 2 + 0) * 32768 + row * 128 + ((((ks << 2) | lq) ^ (row & 7)) << 4);
        return *(const bf16x8*)(base + off);
    };
    auto ldB = [&](int cur, int ni, int ks) {
        int row = wc * 64 + ni * 16 + lr;
        int off = (cur * 2 + 1) * 32768 + row * 128 + ((((ks << 2) | lq) ^ (row & 7)) << 4);
        return *(const bf16x8*)(base + off);
    };

    const int nt = K >> 6;
    stage(0, 0);
    asm volatile("s_waitcnt vmcnt(0)" ::: "memory");
    __builtin_amdgcn_s_barrier();

    bf16x8 af[4][2], bfr[4][2];
    for (int t = 0; t < nt; ++t) {
        const int cur = t & 1;
        // ---- phase 0: frags A mi0-3 + B ni0-1; issue stage(t+1); MFMA Q(0,0)
#pragma unroll
        for (int mi = 0; mi < 4; ++mi) {
            af[mi][0] = ldA(cur, mi, 0); af[mi][1] = ldA(cur, mi, 1);
        }
#pragma unroll
        for (int ni = 0; ni < 2; ++ni) {
            bfr[ni][0] = ldB(cur, ni, 0); bfr[ni][1] = ldB(cur, ni, 1);
        }
        if (t + 1 < nt) stage(cur ^ 1, (t + 1) << 6);
        __builtin_amdgcn_s_barrier();
        __builtin_amdgcn_s_setprio(1);
#pragma unroll
        for (int mi = 0; mi < 4; ++mi)
#pragma unroll
            for (int ni = 0; ni < 2; ++ni)
#pragma unroll
                for (int ks = 0; ks < 2; ++ks)
                    acc[mi][ni] = __builtin_amdgcn_mfma_f32_16x16x32_bf16(
                        af[mi][ks], bfr[ni][ks], acc[mi][ni], 0, 0, 0);
        __builtin_amdgcn_s_setprio(0);
        __builtin_amdgcn_s_barrier();
        // ---- phase 1: frags B ni2-3; MFMA Q(0,1)
#pragma unroll
        for (int ni = 2; ni < 4; ++ni) {
            bfr[ni][0] = ldB(cur, ni, 0); bfr[ni][1] = ldB(cur, ni, 1);
        }
        __builtin_amdgcn_s_barrier();
        __builtin_amdgcn_s_setprio(1);
#pragma unroll
        for (int mi = 0; mi < 4; ++mi)
#pragma unroll
            for (int ni = 2; ni < 4; ++ni)
#pragma unroll
                for (int ks = 0; ks < 2; ++ks)
                    acc[mi][ni] = __builtin_amdgcn_mfma_f32_16x16x32_bf16(
                        af[mi][ks], bfr[ni][ks], acc[mi][ni], 0, 0, 0);
        __builtin_amdgcn_s_setprio(0);
        __builtin_amdgcn_s_barrier();
        // ---- phase 2: frags A mi4-7; MFMA Q(1,1)
#pragma unroll
        for (int mi = 0; mi < 4; ++mi) {
            af[mi][0] = ldA(cur, mi + 4, 0); af[mi][1] = ldA(cur, mi + 4, 1);
        }
        __builtin_amdgcn_s_barrier();
        __builtin_amdgcn_s_setprio(1);
#pragma unroll
        for (int mi = 0; mi < 4; ++mi)
#pragma unroll
            for (int ni = 2; ni < 4; ++ni)
#pragma unroll
                for (int ks = 0; ks < 2; ++ks)
                    acc[mi + 4][ni] = __builtin_amdgcn_mfma_f32_16x16x32_bf16(
                        af[mi][ks], bfr[ni][ks], acc[mi + 4][ni], 0, 0, 0);
        __builtin_amdgcn_s_setprio(0);
        __builtin_amdgcn_s_barrier();
        // ---- phase 3: MFMA Q(1,0) (no reads)
        __builtin_amdgcn_s_setprio(1);
#pragma unroll
        for (int mi = 0; mi < 4; ++mi)
#pragma unroll
            for (int ni = 0; ni < 2; ++ni)
#pragma unroll
                for (int ks = 0; ks < 2; ++ks)
                    acc[mi + 4][ni] = __builtin_amdgcn_mfma_f32_16x16x32_bf16(
                        af[mi][ks], bfr[ni][ks], acc[mi + 4][ni], 0, 0, 0);
        __builtin_amdgcn_s_setprio(0);
        // ---- tile boundary: next buffer landed; all reads of cur done
        asm volatile("s_waitcnt vmcnt(0)" ::: "memory");
        __builtin_amdgcn_s_barrier();
        __builtin_amdgcn_sched_barrier(0);
    }
    // epilogue: C/D layout col=lane&15, row=(lane>>4)*4+reg
#pragma unroll
    for (int mi = 0; mi < 8; ++mi) {
#pragma unroll
        for (int ni = 0; ni < 4; ++ni) {
            int col = (int)bRow0 + wc * 64 + ni * 16 + lr;
            float bv = bias[col];
#pragma unroll
            for (int r2 = 0; r2 < 4; ++r2) {
                size_t row = aRow0 + wr * 128 + mi * 16 + lq * 4 + r2;
                float v = acc[mi][ni][r2] + bv;
                if (MODE == 0) {
                    if (col < 2048) v = (v > 0.f) ? (v + 1.f) : __expf(v);  // elu+1
                    // planar: plane=col>>10 (q/k/v), 32Mi elems per plane
                    size_t idx = ((size_t)(col >> 10)) * 33554432
                                 + row * 1024 + (col & 1023);
                    ((unsigned short*)Cout)[idx] = f2b(v);
                } else {
                    ((unsigned short*)Cout)[row * (size_t)N + col] = f2b(v);
                }
            }
        }
    }
}

// ---------------- kv split-K partials: per (b,h,chunk of 1024 rows) -------
// part[(bh*8+chunk)] = [64x64 kv^T (v-major: [v][d]) | 64 k1]  (4160 floats)
// K/V staged as f32 in LDS (convert once; pad kills write conflicts).
// Planar inputs: kbuf/vbuf are M x 1024 bf16, same row offset for both.
__global__ __launch_bounds__(256) void kv_partial(const unsigned short* __restrict__ kbuf,
                                                  const unsigned short* __restrict__ vbuf,
                                                  float* __restrict__ part) {
    const int bh = blockIdx.x, chunk = blockIdx.y;
    const int b = bh >> 4, h = bh & 15;
    __shared__ float kbf[16][68];
    __shared__ float vbf[16][68];
    const int tid = threadIdx.x;
    const int d0 = (tid >> 4) * 4, v0 = (tid & 15) * 4;
    float acc[4][4] = {};
    float k1a[4] = {0.f, 0.f, 0.f, 0.f};
    const int nn = tid >> 4;
    const int which = (tid >> 3) & 1;
    const int cg = tid & 7;
    const size_t loff = ((size_t)b * 8192 + (size_t)chunk * 1024 + nn) * 1024
                        + h * 64 + cg * 8;
    const unsigned short* src0 = which ? vbuf : kbuf;

    for (int n0 = 0; n0 < 1024; n0 += 16) {
        uint4 val = *(const uint4*)(src0 + loff + (size_t)n0 * 1024);
        float* dst = (which ? &vbf[nn][0] : &kbf[nn][0]) + cg * 8;
        const unsigned short* us = (const unsigned short*)&val;
        float4 f0 = {b2f(us[0]), b2f(us[1]), b2f(us[2]), b2f(us[3])};
        float4 f1 = {b2f(us[4]), b2f(us[5]), b2f(us[6]), b2f(us[7])};
        *(float4*)(dst) = f0;
        *(float4*)(dst + 4) = f1;
        __syncthreads();
#pragma unroll 4
        for (int j = 0; j < 16; ++j) {
            float4 kd = *(const float4*)(&kbf[j][d0]);
            float4 vd = *(const float4*)(&vbf[j][v0]);
            acc[0][0] += kd.x * vd.x; acc[0][1] += kd.x * vd.y; acc[0][2] += kd.x * vd.z; acc[0][3] += kd.x * vd.w;
            acc[1][0] += kd.y * vd.x; acc[1][1] += kd.y * vd.y; acc[1][2] += kd.y * vd.z; acc[1][3] += kd.y * vd.w;
            acc[2][0] += kd.z * vd.x; acc[2][1] += kd.z * vd.y; acc[2][2] += kd.z * vd.z; acc[2][3] += kd.z * vd.w;
            acc[3][0] += kd.w * vd.x; acc[3][1] += kd.w * vd.y; acc[3][2] += kd.w * vd.z; acc[3][3] += kd.w * vd.w;
            if ((tid & 15) == 0) {
                k1a[0] += kd.x; k1a[1] += kd.y; k1a[2] += kd.z; k1a[3] += kd.w;
            }
        }
        __syncthreads();
    }
    float* dst = part + ((size_t)bh * 8 + chunk) * 4160;
#pragma unroll
    for (int i = 0; i < 4; ++i)
#pragma unroll
        for (int jj = 0; jj < 4; ++jj)
            dst[(v0 + jj) * 64 + d0 + i] = acc[i][jj];   // TRANSPOSED: [v][d]
    if ((tid & 15) == 0)
#pragma unroll
        for (int i = 0; i < 4; ++i) dst[4096 + d0 + i] = k1a[i];
}

// ---------------- kv_finish: reduce 8 partials -> bf16 kv^T + f32 k1 ------
__global__ __launch_bounds__(256) void kv_finish(const float* __restrict__ part,
                                                 unsigned short* __restrict__ kvbf,
                                                 float* __restrict__ k1f) {
    const int bh = blockIdx.x;
    const float* src = part + (size_t)bh * 8 * 4160;
    for (int i = threadIdx.x; i < 4096; i += 256) {
        float s = 0.f;
#pragma unroll
        for (int c = 0; c < 8; ++c) s += src[c * 4160 + i];
        kvbf[(size_t)bh * 4096 + i] = f2b(s);
    }
    if (threadIdx.x < 64) {
        float s = 0.f;
#pragma unroll
        for (int c = 0; c < 8; ++c) s += src[c * 4160 + 4096 + threadIdx.x];
        k1f[bh * 64 + threadIdx.x] = s;
    }
}

// ---------------- apply (MFMA): out = (q@kv)/max(q.k1,1e-6), scrambled ----
// Planar q input (M x 1024). att output row-major (scrambled reshape).
__global__ __launch_bounds__(256) void apply_attn(const unsigned short* __restrict__ qbuf,
                                                  const unsigned short* __restrict__ kvbf,
                                                  const float* __restrict__ k1f,
                                                  unsigned short* __restrict__ att) {
    const int nblk = blockIdx.x;
    const int bh = blockIdx.y;
    const int b = bh >> 4, h = bh & 15;
    __shared__ unsigned short kvs[64][64];   // [v][d], slot-swizzled
    __shared__ float k1s[64];
    __shared__ float qk1s[64];
    const int tid = threadIdx.x;
    {
        const int v = tid >> 3, s = tid & 7;
        const uint4* srcv = (const uint4*)(kvbf + (size_t)bh * 4096);
#pragma unroll
        for (int half = 0; half < 2; ++half) {
            int vv = v + half * 32;
            uint4 val = srcv[vv * 8 + s];
            *(uint4*)(&kvs[vv][(s ^ (vv & 7)) * 8]) = val;
        }
        if (tid < 64) k1s[tid] = k1f[bh * 64 + tid];
    }
    __syncthreads();
    const int n0 = nblk * 64;
    const size_t qbase = ((size_t)b * 8192 + n0) * 1024 + h * 64;
    {
        const int row = tid >> 2, dq = (tid & 3) * 16;
        const unsigned short* qp = qbuf + qbase + (size_t)row * 1024 + dq;
        float s = 0.f;
#pragma unroll
        for (int g2 = 0; g2 < 2; ++g2) {
            ushort4 u0 = *(const ushort4*)(qp + g2 * 8);
            ushort4 u1 = *(const ushort4*)(qp + g2 * 8 + 4);
            const float* kp = &k1s[dq + g2 * 8];
            s += b2f(u0.x) * kp[0] + b2f(u0.y) * kp[1] + b2f(u0.z) * kp[2] + b2f(u0.w) * kp[3]
               + b2f(u1.x) * kp[4] + b2f(u1.y) * kp[5] + b2f(u1.z) * kp[6] + b2f(u1.w) * kp[7];
        }
        s += __shfl_xor(s, 1, 64);
        s += __shfl_xor(s, 2, 64);
        if ((tid & 3) == 0) qk1s[row] = s;
    }
    __syncthreads();
    const int w = tid >> 6, lane = tid & 63;
    const int lr = lane & 15, lq = lane >> 4;
    bf16x8 af[2];
#pragma unroll
    for (int ks = 0; ks < 2; ++ks)
        af[ks] = *(const bf16x8*)(qbuf + qbase + (size_t)(w * 16 + lr) * 1024 + ks * 32 + lq * 8);
    f32x4 acc[4] = {};
#pragma unroll
    for (int ni = 0; ni < 4; ++ni)
#pragma unroll
        for (int ks = 0; ks < 2; ++ks) {
            int v = ni * 16 + lr;
            bf16x8 bf = *(const bf16x8*)(&kvs[v][(((ks << 2) | lq) ^ (v & 7)) * 8]);
            acc[ni] = __builtin_amdgcn_mfma_f32_16x16x32_bf16(af[ks], bf, acc[ni], 0, 0, 0);
        }
    unsigned short* dstrow = att + (((size_t)b * 8192) + h * 512 + nblk * 4 + w) * 1024;
#pragma unroll
    for (int r = 0; r < 4; ++r) {
        float rinv = 1.f / fmaxf(qk1s[w * 16 + lq * 4 + r], 1e-6f);
#pragma unroll
        for (int ni = 0; ni < 4; ++ni)
            dstrow[(lq * 4 + r) * 64 + ni * 16 + lr] = f2b(acc[ni][r] * rinv);
    }
}

// ---------------- LayerNorm + residual (bf16 X, bf16 residual) ------------
__global__ __launch_bounds__(256) void ln_residual(const unsigned short* __restrict__ X,
                                                   const unsigned short* __restrict__ Hb,
                                                   const float* __restrict__ gamma,
                                                   const float* __restrict__ beta,
                                                   float* __restrict__ out,
                                                   int nrows) {
    const int lane = threadIdx.x & 63;
    int row = blockIdx.x * 4 + (threadIdx.x >> 6);
    const int rstride = gridDim.x * 4;
    for (; row < nrows; row += rstride) {
        const unsigned short* x = X + (size_t)row * 1024;
        float v[16];
        float s = 0.f, s2 = 0.f;
#pragma unroll
        for (int j = 0; j < 4; ++j) {
            ushort4 u = *(const ushort4*)(x + j * 256 + lane * 4);
            float a = b2f(u.x), b = b2f(u.y), c = b2f(u.z), d = b2f(u.w);
            v[j * 4 + 0] = a; v[j * 4 + 1] = b; v[j * 4 + 2] = c; v[j * 4 + 3] = d;
            s += a + b + c + d;
            s2 += a * a + b * b + c * c + d * d;
        }
#pragma unroll
        for (int o = 32; o > 0; o >>= 1) {
            s  += __shfl_xor(s, o, 64);
            s2 += __shfl_xor(s2, o, 64);
        }
        const float mu = s * (1.f / 1024.f);
        const float var = s2 * (1.f / 1024.f) - mu * mu;   // biased var (jnp.var)
        const float inv = rsqrtf(var + 1e-5f);
        const unsigned short* hrow = Hb + (size_t)row * 1024;
        float* orow = out + (size_t)row * 1024;
#pragma unroll
        for (int j = 0; j < 4; ++j) {
            const int c = j * 256 + lane * 4;
            float4 g = *(const float4*)(gamma + c);
            float4 bt = *(const float4*)(beta + c);
            ushort4 hu = *(const ushort4*)(hrow + c);
            float4 o;
            o.x = (v[j * 4 + 0] - mu) * inv * g.x + bt.x + b2f(hu.x);
            o.y = (v[j * 4 + 1] - mu) * inv * g.y + bt.y + b2f(hu.y);
            o.z = (v[j * 4 + 2] - mu) * inv * g.z + bt.z + b2f(hu.z);
            o.w = (v[j * 4 + 3] - mu) * inv * g.w + bt.w + b2f(hu.w);
            *(float4*)(orow + c) = o;
        }
    }
}

// ---------------------------------------------------------------------------
extern "C" void kernel_launch(void* const* d_in, const int* in_sizes, int n_in,
                              void* d_out, int out_size, void* d_ws, size_t ws_size,
                              hipStream_t stream) {
    const float* H     = (const float*)d_in[0];
    const float* Wqkv  = (const float*)d_in[1];
    const float* bqkv  = (const float*)d_in[2];
    const float* Wproj = (const float*)d_in[3];
    const float* bproj = (const float*)d_in[4];
    const float* gamma = (const float*)d_in[5];
    const float* beta  = (const float*)d_in[6];
    float* out = (float*)d_out;
    char* ws = (char*)d_ws;

    // ws layout (bytes), same 286.4MB footprint:
    // att aliases kbuf (k dead after kv_partial); out2 aliases vbuf (v dead).
    unsigned short* wq_bf = (unsigned short*)(ws);                 //   6,291,456
    unsigned short* wp_bf = (unsigned short*)(ws + 6291456);       //   2,097,152
    unsigned short* hbf   = (unsigned short*)(ws + 8388608);       //  67,108,864
    unsigned short* qbuf  = (unsigned short*)(ws + 75497472);      //  67,108,864
    unsigned short* kbuf  = (unsigned short*)(ws + 142606336);     //  67,108,864
    unsigned short* vbuf  = (unsigned short*)(ws + 209715200);     //  67,108,864
    unsigned short* att   = kbuf;
    unsigned short* out2  = vbuf;
    unsigned short* kvbf  = (unsigned short*)(ws + 276824064);     //     524,288
    float*          k1f   = (float*)(ws + 277348352);              //      16,384
    float*          part  = (float*)(ws + 277889024);              //   8,519,680

    cvt_all<<<1984, 256, 0, stream>>>(H, Wqkv, Wproj, hbf, wq_bf, wp_bf);

    // GEMM1: planar q/k/v out; M=32768 (mb=128), N=3072 -> grid 1536 (%8==0)
    gemm256<0><<<1536, 512, 0, stream>>>(hbf, wq_bf, bqkv, (void*)qbuf,
                                         128, 3072, 1024);

    kv_partial<<<dim3(64, 8), 256, 0, stream>>>(kbuf, vbuf, part);
    kv_finish<<<64, 256, 0, stream>>>(part, kvbf, k1f);

    apply_attn<<<dim3(128, 64), 256, 0, stream>>>(qbuf, kvbf, k1f, att);

    // GEMM2: M=32768 (mb=128), N=1024 -> grid 512 (%8==0); bf16 out
    gemm256<1><<<512, 512, 0, stream>>>(att, wp_bf, bproj, (void*)out2,
                                        128, 1024, 1024);

    ln_residual<<<2048, 256, 0, stream>>>(out2, hbf, gamma, beta, out, 32768);
}